// Round 9
// baseline (312.297 us; speedup 1.0000x reference)
//
#include <hip/hip_runtime.h>

// SectorAttentionV2 on MI355X (gfx950) — round 9
//   Three identical Q-style GEMMs (dbuf + counted vmcnt, 24KB LDS).
//   attn: XCD-group swizzle (one (b,u) clique per XCD) + load reorder with
//   counted vmcnt + raw non-draining barrier for the exchange.

typedef unsigned short u16;
typedef unsigned int u32;
typedef __attribute__((ext_vector_type(8))) short bf16x8;
typedef __attribute__((ext_vector_type(4))) float f32x4;
typedef __attribute__((ext_vector_type(8))) unsigned short u16x8;
typedef __attribute__((ext_vector_type(4))) unsigned int u32x4;

__device__ __forceinline__ u16 f2b(float f) {
  u32 u = __float_as_uint(f);
  return (u16)((u + 0x7FFFu + ((u >> 16) & 1u)) >> 16);  // RNE
}
__device__ __forceinline__ float b2f(u16 v) { return __uint_as_float(((u32)v) << 16); }
__device__ __forceinline__ float b2f_lo(u32 d) { return __uint_as_float(d << 16); }
__device__ __forceinline__ float b2f_hi(u32 d) { return __uint_as_float(d & 0xffff0000u); }
__device__ __forceinline__ u32 cvt_pk(float lo, float hi) {
  u32 r;
  asm("v_cvt_pk_bf16_f32 %0, %1, %2" : "=v"(r) : "v"(lo), "v"(hi));
  return r;
}
#define GLDS(g, l)                                                                     \
  __builtin_amdgcn_global_load_lds((const __attribute__((address_space(1))) void*)(g), \
                                   (__attribute__((address_space(3))) void*)(l), 16, 0, 0)
#define SBAR() __builtin_amdgcn_sched_barrier(0)

// ---------------- weight transpose + cvt ----------------
__global__ __launch_bounds__(256) void wt_kernel(const float* __restrict__ Wq,
                                                 const float* __restrict__ Wk,
                                                 const float* __restrict__ Wv,
                                                 u16* __restrict__ Wt) {
  const float* W = (blockIdx.y == 0) ? Wq : (blockIdx.y == 1) ? Wk : Wv;
  int g = blockIdx.x * 256 + threadIdx.x;
  int n = g >> 9, k = g & 511;
  Wt[(size_t)blockIdx.y * 262144 + g] = f2b(W[k * 512 + n]);
}

// ---------------- bias MLP ----------------
// biasw[((b*8+nh)*4+p)*4+ks][w8192] f32
__global__ __launch_bounds__(256) void bias_kernel(
    const float* __restrict__ xpos, const float* __restrict__ spos,
    const float* __restrict__ pw1, const float* __restrict__ pb1,
    const float* __restrict__ bng, const float* __restrict__ bnb,
    const float* __restrict__ bnm, const float* __restrict__ bnv,
    const float* __restrict__ pw2, const float* __restrict__ pb2,
    float* __restrict__ biasw) {
  int t = threadIdx.x;
  int wl = t & 63, p = t >> 6;
  int n = blockIdx.x * 64 + wl;
  int b = n >> 13, w = n & 8191;

  float Am[16], Bm[16], Cm[16];
#pragma unroll
  for (int m = 0; m < 16; ++m) {
    float scv = bng[m] * rsqrtf(bnv[m] + 1e-5f);
    Am[m] = pw1[2 * m] * scv;
    Bm[m] = pw1[2 * m + 1] * scv;
    Cm[m] = (pb1[m] - bnm[m]) * scv + bnb[m];
  }
  size_t xi = ((size_t)(b * 32768 + p * 8192 + w)) * 2;
  float xp0 = xpos[xi], xp1 = xpos[xi + 1];
#pragma unroll
  for (int ks = 0; ks < 4; ++ks) {
    size_t si = ((size_t)((b * 4 + ks) * 8192 + w)) * 2;
    float r0 = xp0 - spos[si];
    float r1 = xp1 - spos[si + 1];
    float o[8];
#pragma unroll
    for (int oo = 0; oo < 8; ++oo) o[oo] = pb2[oo];
#pragma unroll
    for (int m = 0; m < 16; ++m) {
      float h = fmaxf(Am[m] * r0 + Bm[m] * r1 + Cm[m], 0.f);
#pragma unroll
      for (int oo = 0; oo < 8; ++oo) o[oo] += pw2[oo * 16 + m] * h;
    }
#pragma unroll
    for (int oo = 0; oo < 8; ++oo)
      biasw[((size_t)(((b * 8 + oo) * 4 + p) * 4 + ks)) * 8192 + w] = o[oo];
  }
}

// ---------------- GEMM: BM=128 BN=128 BK=32, dbuf + counted vmcnt ----------------
__global__ __launch_bounds__(256, 3) void gemm_kernel(const float* __restrict__ A,
                                                      const u16* __restrict__ Bt,
                                                      const float* __restrict__ biasv,
                                                      u16* __restrict__ Out) {
  __shared__ u16 lds[24576];  // A dbuf 2x8192 u16 (f32 tile), B dbuf 2x4096 u16
  const int t = threadIdx.x, lane = t & 63, wv = t >> 6;
  const int id = (int)blockIdx.x;
  const int lg = (id & 7) * 256 + (id >> 3);  // XCD bijective swizzle (2048 % 8 == 0)
  const int mt = (lg >> 2) * 128, nt = (lg & 3) * 128;  // n fastest: A-panel L2 reuse
  const int fr = lane & 15, kg = lane >> 4;
  const int wm = (wv & 1) * 64, wn = (wv >> 1) * 64;

  const int arow = lane >> 3;                              // 0..7
  const int agr = (lane & 7) ^ arow;                       // A f32-granule (16B)
  const int brow = lane >> 2;                              // 0..15
  const int bgr = (lane & 3) ^ (brow & 3) ^ ((brow >> 2) & 3);  // B granule (16B)

  const float* Abase = A + (size_t)mt * 512;
  const u16* Bbase = Bt + (size_t)nt * 512;

  f32x4 acc[4][4];
#pragma unroll
  for (int i = 0; i < 4; ++i)
#pragma unroll
    for (int j = 0; j < 4; ++j) acc[i][j] = (f32x4){0.f, 0.f, 0.f, 0.f};

#define STAGEQ(buf, kt)                                                       \
  {                                                                           \
    u16* Ab_ = lds + (buf)*8192;                                              \
    u16* Bb_ = lds + 16384 + (buf)*4096;                                      \
    _Pragma("unroll") for (int ii = 0; ii < 4; ++ii) {                        \
      int inst = wv * 4 + ii;                                                 \
      GLDS(Abase + (size_t)(inst * 8 + arow) * 512 + (kt) + agr * 4,          \
           Ab_ + inst * 512);                                                 \
    }                                                                         \
    _Pragma("unroll") for (int ii = 0; ii < 2; ++ii) {                        \
      int inst = wv * 2 + ii;                                                 \
      GLDS(Bbase + (size_t)(inst * 16 + brow) * 512 + (kt) + bgr * 8,         \
           Bb_ + inst * 512);                                                 \
    }                                                                         \
  }

  STAGEQ(0, 0);

  for (int ki = 0; ki < 16; ++ki) {
    int cur = ki & 1;
    if (ki < 15) {
      STAGEQ(cur ^ 1, (ki + 1) * 32);
      asm volatile("s_waitcnt vmcnt(6)" ::: "memory");
    } else {
      asm volatile("s_waitcnt vmcnt(0)" ::: "memory");
    }
    SBAR();
    __builtin_amdgcn_s_barrier();
    SBAR();

    const u16* Ab = lds + cur * 8192;
    const u16* Bb = lds + 16384 + cur * 4096;
    bf16x8 af[4], bfr[4];
#pragma unroll
    for (int i = 0; i < 4; ++i) {
      int r = wm + i * 16 + fr;
      int p0 = (2 * kg) ^ (r & 7), p1 = (2 * kg + 1) ^ (r & 7);
      f32x4 a0 = *(const f32x4*)&Ab[r * 64 + p0 * 8];
      f32x4 a1 = *(const f32x4*)&Ab[r * 64 + p1 * 8];
      union { bf16x8 v; u32 w[4]; } u;
      u.w[0] = cvt_pk(a0[0], a0[1]);
      u.w[1] = cvt_pk(a0[2], a0[3]);
      u.w[2] = cvt_pk(a1[0], a1[1]);
      u.w[3] = cvt_pk(a1[2], a1[3]);
      af[i] = u.v;
    }
#pragma unroll
    for (int j = 0; j < 4; ++j) {
      int r = wn + j * 16 + fr;
      int pos = kg ^ (r & 3) ^ ((r >> 2) & 3);
      bfr[j] = *(const bf16x8*)&Bb[r * 32 + pos * 8];
    }
#pragma unroll
    for (int i = 0; i < 4; ++i)
#pragma unroll
      for (int j = 0; j < 4; ++j)
        acc[i][j] = __builtin_amdgcn_mfma_f32_16x16x32_bf16(af[i], bfr[j], acc[i][j], 0, 0, 0);

    SBAR();
    __builtin_amdgcn_s_barrier();
    SBAR();
  }
#undef STAGEQ

  // epilogue: stage to LDS (pad 136), flush row-major coalesced (1KB/instr)
  u16* Clds = lds;  // 128*136 = 17408 u16 <= 24576
#pragma unroll
  for (int i = 0; i < 4; ++i)
#pragma unroll
    for (int r = 0; r < 4; ++r) {
      int row = wm + i * 16 + kg * 4 + r;
#pragma unroll
      for (int j = 0; j < 4; ++j) {
        int ch = wn + j * 16 + fr;
        Clds[row * 136 + ch] = f2b(acc[i][j][r] + biasv[nt + ch]);
      }
    }
  __syncthreads();
#pragma unroll
  for (int c = 0; c < 8; ++c) {
    int off = c * 2048 + t * 8;
    int row = off >> 7, col = off & 127;
    *(u16x8*)(Out + (size_t)(mt + row) * 512 + nt + col) = *(const u16x8*)&Clds[row * 136 + col];
  }
}

// ---------------- attention ----------------
// XCD-grouped: one (b,u) clique of 64 blocks (cg x nh) per XCD slot.
// lane = col; wave wv owns d in [wv*16, wv*16+16).
__global__ __launch_bounds__(256, 2) void attn_kernel(const u16* __restrict__ Qt,
                                                      const u16* __restrict__ Kt,
                                                      const u16* __restrict__ Vt,
                                                      const float* __restrict__ biasw,
                                                      float* __restrict__ out) {
  __shared__ u16 kvlds[32768];  // K [256][64] then V [256][64]
  __shared__ float X[4096];     // partial-score exchange [64][64]
  const int t = threadIdx.x, lane = t & 63, wv = t >> 6;
  // bijective: i = ((g>>3)*64 + inner)*8 + (g&7), g = b*16+u, inner = cg*8+nh
  const int i0 = (int)blockIdx.x;
  const int xcd = i0 & 7, qq = i0 >> 3;
  const int g = (qq >> 6) * 8 + xcd, inner = qq & 63;
  const int b = g >> 4, u = g & 15;
  const int cg = inner >> 3, nh = inner & 7;
  const int col = cg * 64 + lane;
  const int chb = nh * 64 + wv * 16;

  // ---- issue order: Q (8) -> K GLDS (8) -> V GLDS (8) -> bias (16) ----
  u32x4 q0[4], q1[4];
#pragma unroll
  for (int p = 0; p < 4; ++p) {
    const u16* qp = Qt + (size_t)(b * 32768 + p * 8192 + u * 512 + col) * 512 + chb;
    q0[p] = *(const u32x4*)qp;
    q1[p] = *(const u32x4*)(qp + 8);
  }
  SBAR();
  {
    const size_t gb = (size_t)(b * 32768 + nh * 4096 + u) * 512 + cg * 64 + (lane & 7) * 8;
#pragma unroll
    for (int ii = 0; ii < 8; ++ii) {
      int i = wv * 8 + ii;
      int r = i * 8 + (lane >> 3);  // LDS row = d*4+ks
      int d = r >> 2, ks = r & 3;
      GLDS(Kt + gb + (size_t)(d * 64 + ks * 16) * 512, &kvlds[i * 512]);
    }
    SBAR();
#pragma unroll
    for (int ii = 0; ii < 8; ++ii) {
      int i = wv * 8 + ii;
      int r = i * 8 + (lane >> 3);
      int d = r >> 2, ks = r & 3;
      GLDS(Vt + gb + (size_t)(d * 64 + ks * 16) * 512, &kvlds[16384 + i * 512]);
    }
    SBAR();
  }
  float br[16];
  const size_t bbase = ((size_t)(b * 8 + nh) * 16) * 8192 + u * 512 + col;
#pragma unroll
  for (int pk = 0; pk < 16; ++pk) br[pk] = biasw[bbase + (size_t)pk * 8192];
  SBAR();

  // wait Q + own-K (V + bias = 24 younger ops still in flight)
  asm volatile("s_waitcnt vmcnt(24)" ::: "memory");
  SBAR();

  // QK^T from K-LDS (this wave's 16 d's)
  float sc[4][4];
#pragma unroll
  for (int p = 0; p < 4; ++p)
#pragma unroll
    for (int k = 0; k < 4; ++k) sc[p][k] = 0.f;
#pragma unroll
  for (int dd = 0; dd < 16; ++dd) {
    int rb = (wv * 16 + dd) * 4;
    float kv[4];
#pragma unroll
    for (int ks = 0; ks < 4; ++ks) kv[ks] = b2f(kvlds[(rb + ks) * 64 + lane]);
    float qd[4];
#pragma unroll
    for (int p = 0; p < 4; ++p) {
      u32 word = (dd < 8) ? q0[p][(dd >> 1) & 3] : q1[p][(dd >> 1) & 3];
      qd[p] = (dd & 1) ? b2f_hi(word) : b2f_lo(word);
    }
#pragma unroll
    for (int p = 0; p < 4; ++p)
#pragma unroll
      for (int ks = 0; ks < 4; ++ks) sc[p][ks] += qd[p] * kv[ks];
  }

  // exchange partial d-slices; raw barrier (V/bias stay in flight)
#pragma unroll
  for (int pk = 0; pk < 16; ++pk) X[(wv * 16 + pk) * 64 + lane] = sc[pk >> 2][pk & 3];
  SBAR();
  asm volatile("s_waitcnt lgkmcnt(0)" ::: "memory");
  __builtin_amdgcn_s_barrier();
  SBAR();
  asm volatile("s_waitcnt vmcnt(0)" ::: "memory");  // bias (and V) landed
  SBAR();

  float a[4][4];
#pragma unroll
  for (int p = 0; p < 4; ++p) {
    float s[4];
#pragma unroll
    for (int ks = 0; ks < 4; ++ks) {
      int pk = p * 4 + ks;
      float tot = X[pk * 64 + lane] + X[(16 + pk) * 64 + lane] + X[(32 + pk) * 64 + lane] +
                  X[(48 + pk) * 64 + lane];
      s[ks] = tot * 0.125f + br[pk];
    }
    float mx = fmaxf(fmaxf(s[0], s[1]), fmaxf(s[2], s[3]));
    float e0 = __expf(s[0] - mx), e1 = __expf(s[1] - mx), e2 = __expf(s[2] - mx),
          e3 = __expf(s[3] - mx);
    float inv = 1.f / (e0 + e1 + e2 + e3);
    a[p][0] = e0 * inv; a[p][1] = e1 * inv; a[p][2] = e2 * inv; a[p][3] = e3 * inv;
  }

  // PV from V-LDS (own-staged rows only)
  float o[4][16];
#pragma unroll
  for (int dd = 0; dd < 16; ++dd) {
    int rb = (wv * 16 + dd) * 4;
    float vv[4];
#pragma unroll
    for (int ks = 0; ks < 4; ++ks) vv[ks] = b2f(kvlds[16384 + (rb + ks) * 64 + lane]);
#pragma unroll
    for (int p = 0; p < 4; ++p)
      o[p][dd] = a[p][0] * vv[0] + a[p][1] * vv[1] + a[p][2] * vv[2] + a[p][3] * vv[3];
  }
#pragma unroll
  for (int p = 0; p < 4; ++p) {
    float* op = out + (size_t)(b * 32768 + p * 8192 + u * 512 + col) * 512 + chb;
#pragma unroll
    for (int c4 = 0; c4 < 4; ++c4) {
      float4 vv = {o[p][c4 * 4 + 0], o[p][c4 * 4 + 1], o[p][c4 * 4 + 2], o[p][c4 * 4 + 3]};
      *(float4*)(op + c4 * 4) = vv;
    }
  }
}

// ---------------- launch ----------------
extern "C" void kernel_launch(void* const* d_in, const int* in_sizes, int n_in,
                              void* d_out, int out_size, void* d_ws, size_t ws_size,
                              hipStream_t stream) {
  (void)in_sizes; (void)n_in; (void)out_size; (void)ws_size;
  const float* s     = (const float*)d_in[0];
  const float* x     = (const float*)d_in[1];
  const float* s_pos = (const float*)d_in[2];
  const float* x_pos = (const float*)d_in[3];
  const float* Wq = (const float*)d_in[4];  const float* bq = (const float*)d_in[5];
  const float* Wk = (const float*)d_in[6];  const float* bk = (const float*)d_in[7];
  const float* Wv = (const float*)d_in[8];  const float* bv = (const float*)d_in[9];
  const float* pw1 = (const float*)d_in[10]; const float* pb1 = (const float*)d_in[11];
  const float* bng = (const float*)d_in[12]; const float* bnb = (const float*)d_in[13];
  const float* bnm = (const float*)d_in[14]; const float* bnv = (const float*)d_in[15];
  const float* pw2 = (const float*)d_in[16]; const float* pb2 = (const float*)d_in[17];
  float* out = (float*)d_out;

  char* ws = (char*)d_ws;
  u16* Qt = (u16*)ws;                        // 67,108,864 B
  u16* Kt = (u16*)(ws + 67108864);           // 67,108,864 B
  u16* Vt = (u16*)(ws + 134217728);          // 67,108,864 B
  float* biasw = (float*)(ws + 201326592);   //  8,388,608 B
  u16* Wt = (u16*)(ws + 209715200);          //  1,572,864 B

  wt_kernel<<<dim3(1024, 3), 256, 0, stream>>>(Wq, Wk, Wv, Wt);
  bias_kernel<<<dim3(256), 256, 0, stream>>>(x_pos, s_pos, pw1, pb1, bng, bnb, bnm, bnv,
                                             pw2, pb2, biasw);
  // K, V first (s L3-reuse across the two), then Q (Qt hot in L3 for attn)
  gemm_kernel<<<dim3(2048), 256, 0, stream>>>(s, Wt + 262144, bk, Kt);
  gemm_kernel<<<dim3(2048), 256, 0, stream>>>(s, Wt + 524288, bv, Vt);
  gemm_kernel<<<dim3(2048), 256, 0, stream>>>(x, Wt, bq, Qt);
  attn_kernel<<<dim3(2048), 256, 0, stream>>>(Qt, Kt, Vt, biasw, out);
}

// Round 10
// 296.434 us; speedup vs baseline: 1.0535x; 1.0535x over previous
//
#include <hip/hip_runtime.h>

// SectorAttentionV2 on MI355X (gfx950) — round 10
//   GEMMs: round-8 config (Q gemm + fused KV gemm, dbuf + counted vmcnt).
//   attn rewritten: wave-per-p, K-only LDS (32KB), V via register loads with
//   lane<->channel transpose through wave-local LDS; 1 barrier, 4 blocks/CU.

typedef unsigned short u16;
typedef unsigned int u32;
typedef __attribute__((ext_vector_type(8))) short bf16x8;
typedef __attribute__((ext_vector_type(4))) float f32x4;
typedef __attribute__((ext_vector_type(8))) unsigned short u16x8;
typedef __attribute__((ext_vector_type(4))) unsigned int u32x4;

__device__ __forceinline__ u16 f2b(float f) {
  u32 u = __float_as_uint(f);
  return (u16)((u + 0x7FFFu + ((u >> 16) & 1u)) >> 16);  // RNE
}
__device__ __forceinline__ float b2f(u16 v) { return __uint_as_float(((u32)v) << 16); }
__device__ __forceinline__ float b2f_lo(u32 d) { return __uint_as_float(d << 16); }
__device__ __forceinline__ float b2f_hi(u32 d) { return __uint_as_float(d & 0xffff0000u); }
__device__ __forceinline__ u32 cvt_pk(float lo, float hi) {
  u32 r;
  asm("v_cvt_pk_bf16_f32 %0, %1, %2" : "=v"(r) : "v"(lo), "v"(hi));
  return r;
}
#define GLDS(g, l)                                                                     \
  __builtin_amdgcn_global_load_lds((const __attribute__((address_space(1))) void*)(g), \
                                   (__attribute__((address_space(3))) void*)(l), 16, 0, 0)
#define SBAR() __builtin_amdgcn_sched_barrier(0)

// ---------------- weight transpose + cvt ----------------
__global__ __launch_bounds__(256) void wt_kernel(const float* __restrict__ Wq,
                                                 const float* __restrict__ Wk,
                                                 const float* __restrict__ Wv,
                                                 u16* __restrict__ Wt) {
  const float* W = (blockIdx.y == 0) ? Wq : (blockIdx.y == 1) ? Wk : Wv;
  int g = blockIdx.x * 256 + threadIdx.x;
  int n = g >> 9, k = g & 511;
  Wt[(size_t)blockIdx.y * 262144 + g] = f2b(W[k * 512 + n]);
}

// ---------------- bias MLP ----------------
// biasw[((b*8+nh)*4+p)*4+ks][w8192] f32
__global__ __launch_bounds__(256) void bias_kernel(
    const float* __restrict__ xpos, const float* __restrict__ spos,
    const float* __restrict__ pw1, const float* __restrict__ pb1,
    const float* __restrict__ bng, const float* __restrict__ bnb,
    const float* __restrict__ bnm, const float* __restrict__ bnv,
    const float* __restrict__ pw2, const float* __restrict__ pb2,
    float* __restrict__ biasw) {
  int t = threadIdx.x;
  int wl = t & 63, p = t >> 6;
  int n = blockIdx.x * 64 + wl;
  int b = n >> 13, w = n & 8191;

  float Am[16], Bm[16], Cm[16];
#pragma unroll
  for (int m = 0; m < 16; ++m) {
    float scv = bng[m] * rsqrtf(bnv[m] + 1e-5f);
    Am[m] = pw1[2 * m] * scv;
    Bm[m] = pw1[2 * m + 1] * scv;
    Cm[m] = (pb1[m] - bnm[m]) * scv + bnb[m];
  }
  size_t xi = ((size_t)(b * 32768 + p * 8192 + w)) * 2;
  float xp0 = xpos[xi], xp1 = xpos[xi + 1];
#pragma unroll
  for (int ks = 0; ks < 4; ++ks) {
    size_t si = ((size_t)((b * 4 + ks) * 8192 + w)) * 2;
    float r0 = xp0 - spos[si];
    float r1 = xp1 - spos[si + 1];
    float o[8];
#pragma unroll
    for (int oo = 0; oo < 8; ++oo) o[oo] = pb2[oo];
#pragma unroll
    for (int m = 0; m < 16; ++m) {
      float h = fmaxf(Am[m] * r0 + Bm[m] * r1 + Cm[m], 0.f);
#pragma unroll
      for (int oo = 0; oo < 8; ++oo) o[oo] += pw2[oo * 16 + m] * h;
    }
#pragma unroll
    for (int oo = 0; oo < 8; ++oo)
      biasw[((size_t)(((b * 8 + oo) * 4 + p) * 4 + ks)) * 8192 + w] = o[oo];
  }
}

// ---------------- Q GEMM: BM=128 BN=128 BK=32, dbuf + counted vmcnt ----------------
__global__ __launch_bounds__(256, 3) void gemm_kernel(const float* __restrict__ A,
                                                      const u16* __restrict__ Bt,
                                                      const float* __restrict__ biasv,
                                                      u16* __restrict__ Out) {
  __shared__ u16 lds[24576];
  const int t = threadIdx.x, lane = t & 63, wv = t >> 6;
  const int id = (int)blockIdx.x;
  const int lg = (id & 7) * 256 + (id >> 3);
  const int mt = (lg >> 2) * 128, nt = (lg & 3) * 128;
  const int fr = lane & 15, kg = lane >> 4;
  const int wm = (wv & 1) * 64, wn = (wv >> 1) * 64;

  const int arow = lane >> 3;
  const int agr = (lane & 7) ^ arow;
  const int brow = lane >> 2;
  const int bgr = (lane & 3) ^ (brow & 3) ^ ((brow >> 2) & 3);

  const float* Abase = A + (size_t)mt * 512;
  const u16* Bbase = Bt + (size_t)nt * 512;

  f32x4 acc[4][4];
#pragma unroll
  for (int i = 0; i < 4; ++i)
#pragma unroll
    for (int j = 0; j < 4; ++j) acc[i][j] = (f32x4){0.f, 0.f, 0.f, 0.f};

#define STAGEQ(buf, kt)                                                       \
  {                                                                           \
    u16* Ab_ = lds + (buf)*8192;                                              \
    u16* Bb_ = lds + 16384 + (buf)*4096;                                      \
    _Pragma("unroll") for (int ii = 0; ii < 4; ++ii) {                        \
      int inst = wv * 4 + ii;                                                 \
      GLDS(Abase + (size_t)(inst * 8 + arow) * 512 + (kt) + agr * 4,          \
           Ab_ + inst * 512);                                                 \
    }                                                                         \
    _Pragma("unroll") for (int ii = 0; ii < 2; ++ii) {                        \
      int inst = wv * 2 + ii;                                                 \
      GLDS(Bbase + (size_t)(inst * 16 + brow) * 512 + (kt) + bgr * 8,         \
           Bb_ + inst * 512);                                                 \
    }                                                                         \
  }

  STAGEQ(0, 0);

  for (int ki = 0; ki < 16; ++ki) {
    int cur = ki & 1;
    if (ki < 15) {
      STAGEQ(cur ^ 1, (ki + 1) * 32);
      asm volatile("s_waitcnt vmcnt(6)" ::: "memory");
    } else {
      asm volatile("s_waitcnt vmcnt(0)" ::: "memory");
    }
    SBAR();
    __builtin_amdgcn_s_barrier();
    SBAR();

    const u16* Ab = lds + cur * 8192;
    const u16* Bb = lds + 16384 + cur * 4096;
    bf16x8 af[4], bfr[4];
#pragma unroll
    for (int i = 0; i < 4; ++i) {
      int r = wm + i * 16 + fr;
      int p0 = (2 * kg) ^ (r & 7), p1 = (2 * kg + 1) ^ (r & 7);
      f32x4 a0 = *(const f32x4*)&Ab[r * 64 + p0 * 8];
      f32x4 a1 = *(const f32x4*)&Ab[r * 64 + p1 * 8];
      union { bf16x8 v; u32 w[4]; } u;
      u.w[0] = cvt_pk(a0[0], a0[1]);
      u.w[1] = cvt_pk(a0[2], a0[3]);
      u.w[2] = cvt_pk(a1[0], a1[1]);
      u.w[3] = cvt_pk(a1[2], a1[3]);
      af[i] = u.v;
    }
#pragma unroll
    for (int j = 0; j < 4; ++j) {
      int r = wn + j * 16 + fr;
      int pos = kg ^ (r & 3) ^ ((r >> 2) & 3);
      bfr[j] = *(const bf16x8*)&Bb[r * 32 + pos * 8];
    }
#pragma unroll
    for (int i = 0; i < 4; ++i)
#pragma unroll
      for (int j = 0; j < 4; ++j)
        acc[i][j] = __builtin_amdgcn_mfma_f32_16x16x32_bf16(af[i], bfr[j], acc[i][j], 0, 0, 0);

    SBAR();
    __builtin_amdgcn_s_barrier();
    SBAR();
  }
#undef STAGEQ

  u16* Clds = lds;
#pragma unroll
  for (int i = 0; i < 4; ++i)
#pragma unroll
    for (int r = 0; r < 4; ++r) {
      int row = wm + i * 16 + kg * 4 + r;
#pragma unroll
      for (int j = 0; j < 4; ++j) {
        int ch = wn + j * 16 + fr;
        Clds[row * 136 + ch] = f2b(acc[i][j][r] + biasv[nt + ch]);
      }
    }
  __syncthreads();
#pragma unroll
  for (int c = 0; c < 8; ++c) {
    int off = c * 2048 + t * 8;
    int row = off >> 7, col = off & 127;
    *(u16x8*)(Out + (size_t)(mt + row) * 512 + nt + col) = *(const u16x8*)&Clds[row * 136 + col];
  }
}

// ---------------- fused K+V GEMM (round-8) ----------------
__global__ __launch_bounds__(256, 2) void gemmkv_kernel(const float* __restrict__ A,
                                                        const u16* __restrict__ BtK,
                                                        const u16* __restrict__ BtV,
                                                        const float* __restrict__ bK,
                                                        const float* __restrict__ bV,
                                                        u16* __restrict__ OutK,
                                                        u16* __restrict__ OutV) {
  __shared__ u16 lds[32768];
  const int t = threadIdx.x, lane = t & 63, wv = t >> 6;
  const int id = (int)blockIdx.x;
  const int lg = (id & 7) * 256 + (id >> 3);
  const int mt = (lg >> 2) * 128, nt = (lg & 3) * 128;
  const int fr = lane & 15, kg = lane >> 4;
  const int wm = (wv & 1) * 64, wn = (wv >> 1) * 64;

  const int arow = lane >> 3;
  const int agr = (lane & 7) ^ arow;
  const int brow = lane >> 2;
  const int bgr = (lane & 3) ^ (brow & 3) ^ ((brow >> 2) & 3);

  const float* Abase = A + (size_t)mt * 512;
  const u16* BbaseK = BtK + (size_t)nt * 512;
  const u16* BbaseV = BtV + (size_t)nt * 512;

  f32x4 accK[4][4], accV[4][4];
#pragma unroll
  for (int i = 0; i < 4; ++i)
#pragma unroll
    for (int j = 0; j < 4; ++j) {
      accK[i][j] = (f32x4){0.f, 0.f, 0.f, 0.f};
      accV[i][j] = (f32x4){0.f, 0.f, 0.f, 0.f};
    }

#define STAGEKV(buf, kt)                                                      \
  {                                                                           \
    u16* Ab_ = lds + (buf)*8192;                                              \
    u16* Bk_ = lds + 16384 + (buf)*4096;                                      \
    u16* Bv_ = lds + 24576 + (buf)*4096;                                      \
    _Pragma("unroll") for (int ii = 0; ii < 4; ++ii) {                        \
      int inst = wv * 4 + ii;                                                 \
      GLDS(Abase + (size_t)(inst * 8 + arow) * 512 + (kt) + agr * 4,          \
           Ab_ + inst * 512);                                                 \
    }                                                                         \
    _Pragma("unroll") for (int ii = 0; ii < 2; ++ii) {                        \
      int inst = wv * 2 + ii;                                                 \
      GLDS(BbaseK + (size_t)(inst * 16 + brow) * 512 + (kt) + bgr * 8,        \
           Bk_ + inst * 512);                                                 \
      GLDS(BbaseV + (size_t)(inst * 16 + brow) * 512 + (kt) + bgr * 8,        \
           Bv_ + inst * 512);                                                 \
    }                                                                         \
  }

  STAGEKV(0, 0);

  for (int ki = 0; ki < 16; ++ki) {
    int cur = ki & 1;
    if (ki < 15) {
      STAGEKV(cur ^ 1, (ki + 1) * 32);
      asm volatile("s_waitcnt vmcnt(8)" ::: "memory");
    } else {
      asm volatile("s_waitcnt vmcnt(0)" ::: "memory");
    }
    SBAR();
    __builtin_amdgcn_s_barrier();
    SBAR();

    const u16* Ab = lds + cur * 8192;
    const u16* Bk = lds + 16384 + cur * 4096;
    const u16* Bv = lds + 24576 + cur * 4096;
    bf16x8 af[4], bk8[4], bv8[4];
#pragma unroll
    for (int i = 0; i < 4; ++i) {
      int r = wm + i * 16 + fr;
      int p0 = (2 * kg) ^ (r & 7), p1 = (2 * kg + 1) ^ (r & 7);
      f32x4 a0 = *(const f32x4*)&Ab[r * 64 + p0 * 8];
      f32x4 a1 = *(const f32x4*)&Ab[r * 64 + p1 * 8];
      union { bf16x8 v; u32 w[4]; } u;
      u.w[0] = cvt_pk(a0[0], a0[1]);
      u.w[1] = cvt_pk(a0[2], a0[3]);
      u.w[2] = cvt_pk(a1[0], a1[1]);
      u.w[3] = cvt_pk(a1[2], a1[3]);
      af[i] = u.v;
    }
#pragma unroll
    for (int j = 0; j < 4; ++j) {
      int r = wn + j * 16 + fr;
      int pos = kg ^ (r & 3) ^ ((r >> 2) & 3);
      bk8[j] = *(const bf16x8*)&Bk[r * 32 + pos * 8];
      bv8[j] = *(const bf16x8*)&Bv[r * 32 + pos * 8];
    }
#pragma unroll
    for (int i = 0; i < 4; ++i)
#pragma unroll
      for (int j = 0; j < 4; ++j) {
        accK[i][j] = __builtin_amdgcn_mfma_f32_16x16x32_bf16(af[i], bk8[j], accK[i][j], 0, 0, 0);
        accV[i][j] = __builtin_amdgcn_mfma_f32_16x16x32_bf16(af[i], bv8[j], accV[i][j], 0, 0, 0);
      }

    SBAR();
    __builtin_amdgcn_s_barrier();
    SBAR();
  }
#undef STAGEKV

  u16* Clds = lds;
#pragma unroll
  for (int mat = 0; mat < 2; ++mat) {
    const float* bias = mat ? bV : bK;
    u16* Outp = mat ? OutV : OutK;
    __syncthreads();
#pragma unroll
    for (int i = 0; i < 4; ++i)
#pragma unroll
      for (int r = 0; r < 4; ++r) {
        int row = wm + i * 16 + kg * 4 + r;
#pragma unroll
        for (int j = 0; j < 4; ++j) {
          int ch = wn + j * 16 + fr;
          float v = mat ? accV[i][j][r] : accK[i][j][r];
          Clds[row * 136 + ch] = f2b(v + bias[nt + ch]);
        }
      }
    __syncthreads();
#pragma unroll
    for (int c = 0; c < 8; ++c) {
      int off = c * 2048 + t * 8;
      int row = off >> 7, col = off & 127;
      *(u16x8*)(Outp + (size_t)(mt + row) * 512 + nt + col) = *(const u16x8*)&Clds[row * 136 + col];
    }
  }
}

// ---------------- attention: wave-per-p, K-only LDS, transposed PV ----------------
// block = (b,u,cg,nh) via XCD clique swizzle; wave wv = p; QK lane = col,
// PV lane = output channel (d).
__global__ __launch_bounds__(256, 3) void attn_kernel(const u16* __restrict__ Qt,
                                                      const u16* __restrict__ Kt,
                                                      const u16* __restrict__ Vt,
                                                      const float* __restrict__ biasw,
                                                      float* __restrict__ out) {
  __shared__ u16 klds[16384];        // K [256 rows = d*4+ks][64 cols]  (32 KB)
  __shared__ float alds[4][4][64];   // per-wave a[ks][col]             (4 KB)
  const int t = threadIdx.x, lane = t & 63, wv = t >> 6;
  const int i0 = (int)blockIdx.x;
  const int xcd = i0 & 7, qq = i0 >> 3;
  const int g = (qq >> 6) * 8 + xcd, inner = qq & 63;
  const int b = g >> 4, u = g & 15;
  const int cg = inner >> 3, nh = inner & 7;
  const int col = cg * 64 + lane;

  // Q for this wave's p (=wv): all 64 head channels, 128B per lane
  u32x4 qv[8];
  {
    const u16* qp = Qt + (size_t)(b * 32768 + wv * 8192 + u * 512 + col) * 512 + nh * 64;
#pragma unroll
    for (int i = 0; i < 8; ++i) qv[i] = *(const u32x4*)(qp + i * 8);
  }
  SBAR();
  // K staging: each wave stages rows [wv*64, wv*64+64) (8 GLDS)
  {
    const size_t gb = (size_t)(b * 32768 + nh * 4096 + u) * 512 + cg * 64 + (lane & 7) * 8;
#pragma unroll
    for (int ii = 0; ii < 8; ++ii) {
      int i = wv * 8 + ii;
      int r = i * 8 + (lane >> 3);  // LDS row = d*4+ks
      int d = r >> 2, ks = r & 3;
      GLDS(Kt + gb + (size_t)(d * 64 + ks * 16) * 512, &klds[i * 512]);
    }
  }
  SBAR();
  // bias: this wave's 4 ks values
  float br[4];
  {
    const size_t bb = (((size_t)(b * 8 + nh) * 16) + wv * 4) * 8192 + u * 512 + col;
#pragma unroll
    for (int ks = 0; ks < 4; ++ks) br[ks] = biasw[bb + (size_t)ks * 8192];
  }
  SBAR();
  // wait Q + own K GLDS (bias 4 younger stays in flight), then block barrier
  asm volatile("s_waitcnt vmcnt(4)" ::: "memory");
  SBAR();
  __builtin_amdgcn_s_barrier();
  SBAR();

  // QK^T over all 64 d (this wave's p only)
  float sc[4] = {0.f, 0.f, 0.f, 0.f};
#pragma unroll
  for (int d = 0; d < 64; ++d) {
    u32 word = qv[d >> 3][(d >> 1) & 3];
    float qd = (d & 1) ? b2f_hi(word) : b2f_lo(word);
    int rb = d * 4;
#pragma unroll
    for (int ks = 0; ks < 4; ++ks) sc[ks] += qd * b2f(klds[(rb + ks) * 64 + lane]);
  }

  // softmax (needs bias)
  asm volatile("s_waitcnt vmcnt(0)" ::: "memory");
  SBAR();
  float a[4];
  {
    float s0 = sc[0] * 0.125f + br[0];
    float s1 = sc[1] * 0.125f + br[1];
    float s2 = sc[2] * 0.125f + br[2];
    float s3 = sc[3] * 0.125f + br[3];
    float mx = fmaxf(fmaxf(s0, s1), fmaxf(s2, s3));
    float e0 = __expf(s0 - mx), e1 = __expf(s1 - mx), e2 = __expf(s2 - mx), e3 = __expf(s3 - mx);
    float inv = 1.f / (e0 + e1 + e2 + e3);
    a[0] = e0 * inv; a[1] = e1 * inv; a[2] = e2 * inv; a[3] = e3 * inv;
  }

  // transpose a through wave-local LDS (no barrier: same wave writes+reads)
#pragma unroll
  for (int ks = 0; ks < 4; ++ks) alds[wv][ks][lane] = a[ks];

  // PV: lane = output channel d; V read as contiguous 128B rows from global
  const u16* vp = Vt + (size_t)(b * 32768 + nh * 4096 + lane * 64 + u) * 512 + cg * 64;
  float* op = out + (size_t)(b * 32768 + wv * 8192 + u * 512 + cg * 64) * 512 + nh * 64 + lane;
#pragma unroll
  for (int cc = 0; cc < 4; ++cc) {
    u32x4 vr[4][2];
#pragma unroll
    for (int ks = 0; ks < 4; ++ks) {
#pragma unroll
      for (int h = 0; h < 2; ++h)
        vr[ks][h] = *(const u32x4*)(vp + (size_t)ks * 8192 + cc * 16 + h * 8);
    }
#pragma unroll
    for (int c16 = 0; c16 < 16; ++c16) {
      int c = cc * 16 + c16;
      int h = c16 >> 3, word = (c16 >> 1) & 3;
      float o = 0.f;
#pragma unroll
      for (int ks = 0; ks < 4; ++ks) {
        u32 wrd = vr[ks][h][word];
        float vvv = (c16 & 1) ? b2f_hi(wrd) : b2f_lo(wrd);
        o += alds[wv][ks][c] * vvv;
      }
      op[(size_t)c * 512] = o;
    }
  }
}

// ---------------- launch ----------------
extern "C" void kernel_launch(void* const* d_in, const int* in_sizes, int n_in,
                              void* d_out, int out_size, void* d_ws, size_t ws_size,
                              hipStream_t stream) {
  (void)in_sizes; (void)n_in; (void)out_size; (void)ws_size;
  const float* s     = (const float*)d_in[0];
  const float* x     = (const float*)d_in[1];
  const float* s_pos = (const float*)d_in[2];
  const float* x_pos = (const float*)d_in[3];
  const float* Wq = (const float*)d_in[4];  const float* bq = (const float*)d_in[5];
  const float* Wk = (const float*)d_in[6];  const float* bk = (const float*)d_in[7];
  const float* Wv = (const float*)d_in[8];  const float* bv = (const float*)d_in[9];
  const float* pw1 = (const float*)d_in[10]; const float* pb1 = (const float*)d_in[11];
  const float* bng = (const float*)d_in[12]; const float* bnb = (const float*)d_in[13];
  const float* bnm = (const float*)d_in[14]; const float* bnv = (const float*)d_in[15];
  const float* pw2 = (const float*)d_in[16]; const float* pb2 = (const float*)d_in[17];
  float* out = (float*)d_out;

  char* ws = (char*)d_ws;
  u16* Qt = (u16*)ws;                        // 67,108,864 B
  u16* Kt = (u16*)(ws + 67108864);           // 67,108,864 B
  u16* Vt = (u16*)(ws + 134217728);          // 67,108,864 B
  float* biasw = (float*)(ws + 201326592);   //  8,388,608 B
  u16* Wt = (u16*)(ws + 209715200);          //  1,572,864 B

  wt_kernel<<<dim3(1024, 3), 256, 0, stream>>>(Wq, Wk, Wv, Wt);
  bias_kernel<<<dim3(256), 256, 0, stream>>>(x_pos, s_pos, pw1, pb1, bng, bnb, bnm, bnv,
                                             pw2, pb2, biasw);
  gemm_kernel<<<dim3(2048), 256, 0, stream>>>(x, Wt, bq, Qt);
  gemmkv_kernel<<<dim3(2048), 256, 0, stream>>>(s, Wt + 262144, Wt + 524288, bk, bv, Kt, Vt);
  attn_kernel<<<dim3(2048), 256, 0, stream>>>(Qt, Kt, Vt, biasw, out);
}

// Round 11
// 277.396 us; speedup vs baseline: 1.1258x; 1.0686x over previous
//
#include <hip/hip_runtime.h>

// SectorAttentionV2 on MI355X (gfx950) — round 11
//   K/V projections fused INTO the attention kernel: each block (b,u,cg,nh)
//   computes its 256x64 K/V panels via MFMA (s staged f32 by global_load_lds,
//   counted vmcnt dbuf), writes them to LDS, then runs QK/softmax/PV.
//   Q-GEMM, wt, bias unchanged. gemmkv deleted.

typedef unsigned short u16;
typedef unsigned int u32;
typedef __attribute__((ext_vector_type(8))) short bf16x8;
typedef __attribute__((ext_vector_type(4))) float f32x4;
typedef __attribute__((ext_vector_type(8))) unsigned short u16x8;
typedef __attribute__((ext_vector_type(4))) unsigned short u16x4;
typedef __attribute__((ext_vector_type(4))) unsigned int u32x4;

__device__ __forceinline__ u16 f2b(float f) {
  u32 u = __float_as_uint(f);
  return (u16)((u + 0x7FFFu + ((u >> 16) & 1u)) >> 16);  // RNE
}
__device__ __forceinline__ float b2f(u16 v) { return __uint_as_float(((u32)v) << 16); }
__device__ __forceinline__ float b2f_lo(u32 d) { return __uint_as_float(d << 16); }
__device__ __forceinline__ float b2f_hi(u32 d) { return __uint_as_float(d & 0xffff0000u); }
__device__ __forceinline__ u32 cvt_pk(float lo, float hi) {
  u32 r;
  asm("v_cvt_pk_bf16_f32 %0, %1, %2" : "=v"(r) : "v"(lo), "v"(hi));
  return r;
}
#define GLDS(g, l)                                                                     \
  __builtin_amdgcn_global_load_lds((const __attribute__((address_space(1))) void*)(g), \
                                   (__attribute__((address_space(3))) void*)(l), 16, 0, 0)
#define SBAR() __builtin_amdgcn_sched_barrier(0)

// ---------------- weight transpose + cvt ----------------
__global__ __launch_bounds__(256) void wt_kernel(const float* __restrict__ Wq,
                                                 const float* __restrict__ Wk,
                                                 const float* __restrict__ Wv,
                                                 u16* __restrict__ Wt) {
  const float* W = (blockIdx.y == 0) ? Wq : (blockIdx.y == 1) ? Wk : Wv;
  int g = blockIdx.x * 256 + threadIdx.x;
  int n = g >> 9, k = g & 511;
  Wt[(size_t)blockIdx.y * 262144 + g] = f2b(W[k * 512 + n]);
}

// ---------------- bias MLP ----------------
// biasw[((b*8+nh)*4+p)*4+ks][w8192] f32
__global__ __launch_bounds__(256) void bias_kernel(
    const float* __restrict__ xpos, const float* __restrict__ spos,
    const float* __restrict__ pw1, const float* __restrict__ pb1,
    const float* __restrict__ bng, const float* __restrict__ bnb,
    const float* __restrict__ bnm, const float* __restrict__ bnv,
    const float* __restrict__ pw2, const float* __restrict__ pb2,
    float* __restrict__ biasw) {
  int t = threadIdx.x;
  int wl = t & 63, p = t >> 6;
  int n = blockIdx.x * 64 + wl;
  int b = n >> 13, w = n & 8191;

  float Am[16], Bm[16], Cm[16];
#pragma unroll
  for (int m = 0; m < 16; ++m) {
    float scv = bng[m] * rsqrtf(bnv[m] + 1e-5f);
    Am[m] = pw1[2 * m] * scv;
    Bm[m] = pw1[2 * m + 1] * scv;
    Cm[m] = (pb1[m] - bnm[m]) * scv + bnb[m];
  }
  size_t xi = ((size_t)(b * 32768 + p * 8192 + w)) * 2;
  float xp0 = xpos[xi], xp1 = xpos[xi + 1];
#pragma unroll
  for (int ks = 0; ks < 4; ++ks) {
    size_t si = ((size_t)((b * 4 + ks) * 8192 + w)) * 2;
    float r0 = xp0 - spos[si];
    float r1 = xp1 - spos[si + 1];
    float o[8];
#pragma unroll
    for (int oo = 0; oo < 8; ++oo) o[oo] = pb2[oo];
#pragma unroll
    for (int m = 0; m < 16; ++m) {
      float h = fmaxf(Am[m] * r0 + Bm[m] * r1 + Cm[m], 0.f);
#pragma unroll
      for (int oo = 0; oo < 8; ++oo) o[oo] += pw2[oo * 16 + m] * h;
    }
#pragma unroll
    for (int oo = 0; oo < 8; ++oo)
      biasw[((size_t)(((b * 8 + oo) * 4 + p) * 4 + ks)) * 8192 + w] = o[oo];
  }
}

// ---------------- Q GEMM: BM=128 BN=128 BK=32, dbuf + counted vmcnt ----------------
__global__ __launch_bounds__(256, 3) void gemm_kernel(const float* __restrict__ A,
                                                      const u16* __restrict__ Bt,
                                                      const float* __restrict__ biasv,
                                                      u16* __restrict__ Out) {
  __shared__ u16 lds[24576];
  const int t = threadIdx.x, lane = t & 63, wv = t >> 6;
  const int id = (int)blockIdx.x;
  const int lg = (id & 7) * 256 + (id >> 3);
  const int mt = (lg >> 2) * 128, nt = (lg & 3) * 128;
  const int fr = lane & 15, kg = lane >> 4;
  const int wm = (wv & 1) * 64, wn = (wv >> 1) * 64;

  const int arow = lane >> 3;
  const int agr = (lane & 7) ^ arow;
  const int brow = lane >> 2;
  const int bgr = (lane & 3) ^ (brow & 3) ^ ((brow >> 2) & 3);

  const float* Abase = A + (size_t)mt * 512;
  const u16* Bbase = Bt + (size_t)nt * 512;

  f32x4 acc[4][4];
#pragma unroll
  for (int i = 0; i < 4; ++i)
#pragma unroll
    for (int j = 0; j < 4; ++j) acc[i][j] = (f32x4){0.f, 0.f, 0.f, 0.f};

#define STAGEQ(buf, kt)                                                       \
  {                                                                           \
    u16* Ab_ = lds + (buf)*8192;                                              \
    u16* Bb_ = lds + 16384 + (buf)*4096;                                      \
    _Pragma("unroll") for (int ii = 0; ii < 4; ++ii) {                        \
      int inst = wv * 4 + ii;                                                 \
      GLDS(Abase + (size_t)(inst * 8 + arow) * 512 + (kt) + agr * 4,          \
           Ab_ + inst * 512);                                                 \
    }                                                                         \
    _Pragma("unroll") for (int ii = 0; ii < 2; ++ii) {                        \
      int inst = wv * 2 + ii;                                                 \
      GLDS(Bbase + (size_t)(inst * 16 + brow) * 512 + (kt) + bgr * 8,         \
           Bb_ + inst * 512);                                                 \
    }                                                                         \
  }

  STAGEQ(0, 0);

  for (int ki = 0; ki < 16; ++ki) {
    int cur = ki & 1;
    if (ki < 15) {
      STAGEQ(cur ^ 1, (ki + 1) * 32);
      asm volatile("s_waitcnt vmcnt(6)" ::: "memory");
    } else {
      asm volatile("s_waitcnt vmcnt(0)" ::: "memory");
    }
    SBAR();
    __builtin_amdgcn_s_barrier();
    SBAR();

    const u16* Ab = lds + cur * 8192;
    const u16* Bb = lds + 16384 + cur * 4096;
    bf16x8 af[4], bfr[4];
#pragma unroll
    for (int i = 0; i < 4; ++i) {
      int r = wm + i * 16 + fr;
      int p0 = (2 * kg) ^ (r & 7), p1 = p0 ^ 1;
      f32x4 a0 = *(const f32x4*)&Ab[r * 64 + p0 * 8];
      f32x4 a1 = *(const f32x4*)&Ab[r * 64 + p1 * 8];
      union { bf16x8 v; u32 w[4]; } uu;
      uu.w[0] = cvt_pk(a0[0], a0[1]);
      uu.w[1] = cvt_pk(a0[2], a0[3]);
      uu.w[2] = cvt_pk(a1[0], a1[1]);
      uu.w[3] = cvt_pk(a1[2], a1[3]);
      af[i] = uu.v;
    }
#pragma unroll
    for (int j = 0; j < 4; ++j) {
      int r = wn + j * 16 + fr;
      int pos = kg ^ (r & 3) ^ ((r >> 2) & 3);
      bfr[j] = *(const bf16x8*)&Bb[r * 32 + pos * 8];
    }
#pragma unroll
    for (int i = 0; i < 4; ++i)
#pragma unroll
      for (int j = 0; j < 4; ++j)
        acc[i][j] = __builtin_amdgcn_mfma_f32_16x16x32_bf16(af[i], bfr[j], acc[i][j], 0, 0, 0);

    SBAR();
    __builtin_amdgcn_s_barrier();
    SBAR();
  }
#undef STAGEQ

  u16* Clds = lds;
#pragma unroll
  for (int i = 0; i < 4; ++i)
#pragma unroll
    for (int r = 0; r < 4; ++r) {
      int row = wm + i * 16 + kg * 4 + r;
#pragma unroll
      for (int j = 0; j < 4; ++j) {
        int ch = wn + j * 16 + fr;
        Clds[row * 136 + ch] = f2b(acc[i][j][r] + biasv[nt + ch]);
      }
    }
  __syncthreads();
#pragma unroll
  for (int c = 0; c < 8; ++c) {
    int off = c * 2048 + t * 8;
    int row = off >> 7, col = off & 127;
    *(u16x8*)(Out + (size_t)(mt + row) * 512 + nt + col) = *(const u16x8*)&Clds[row * 136 + col];
  }
}

// ---------------- fused KV-projection + attention ----------------
// block (b,u,cg,nh), 512 threads (8 waves). Phase 1: K/V panels (256x64,
// K=512) via MFMA, s staged f32 dbuf. Phase 2: panels -> LDS (K stride-68;
// V transposed [c][256+pad]). Phase 3: QK/softmax/PV, waves = (p, dh).
__global__ __launch_bounds__(512, 2) void fused_attn_kernel(
    const float* __restrict__ s, const u16* __restrict__ WtK, const u16* __restrict__ WtV,
    const float* __restrict__ bK, const float* __restrict__ bV,
    const u16* __restrict__ Qt, const float* __restrict__ biasw, float* __restrict__ out) {
  __shared__ __align__(16) char LDS[150528];
  // offsets: S dbuf 0..65536, Wk 65536..73728, Wv 73728..81920,
  //          Klds 81920 (256x68 u16), Vlds 116736 (64x264 u16)
  float* Xf = (float*)LDS;              // P3 overlay: [8 wv][4 ks][64 c]
  float* alds = (float*)(LDS + 8192);   // P3 overlay: [4 p][4 ks][64 c]
  u16* Klds = (u16*)(LDS + 81920);
  u16* Vlds = (u16*)(LDS + 116736);

  const int t = threadIdx.x, lane = t & 63, wv = t >> 6;
  const int i0 = (int)blockIdx.x;
  const int xcd = i0 & 7, qq = i0 >> 3;
  const int g = (qq >> 6) * 8 + xcd, inner = qq & 63;
  const int b = g >> 4, u = g & 15;
  const int cg = inner >> 3, nh = inner & 7;
  const int fr = lane & 15, kg = lane >> 4;
  const int p3p = wv >> 1, dh = wv & 1;

  // ---- early loads: Q(4) + bias(4) + bk(4) + bv(4) ----
  u32x4 qv[4];
  {
    const u16* qp =
        Qt + (size_t)(b * 32768 + p3p * 8192 + u * 512 + cg * 64 + lane) * 512 + nh * 64 + dh * 32;
#pragma unroll
    for (int i = 0; i < 4; ++i) qv[i] = *(const u32x4*)(qp + i * 8);
  }
  float br[4];
  {
    const size_t bb = ((size_t)((b * 8 + nh) * 16 + p3p * 4)) * 8192 + u * 512 + cg * 64 + lane;
#pragma unroll
    for (int ks = 0; ks < 4; ++ks) br[ks] = biasw[bb + (size_t)ks * 8192];
  }
  float bkr[4], bvr[4];
#pragma unroll
  for (int j = 0; j < 4; ++j) {
    bkr[j] = bK[cg * 64 + j * 16 + fr];
    bvr[j] = bV[cg * 64 + j * 16 + fr];
  }
  SBAR();

  f32x4 accK[2][4], accV[2][4];
#pragma unroll
  for (int i = 0; i < 2; ++i)
#pragma unroll
    for (int j = 0; j < 4; ++j) {
      accK[i][j] = (f32x4){0.f, 0.f, 0.f, 0.f};
      accV[i][j] = (f32x4){0.f, 0.f, 0.f, 0.f};
    }

  // staging geometry
  const int sr_lane = lane >> 3;                 // row-within-inst for s
  const int wrow_l = lane >> 2;                  // row-within-inst for W

#define STAGEF(buf, kt)                                                                \
  {                                                                                    \
    char* Sb_ = LDS + (buf)*32768;                                                     \
    _Pragma("unroll") for (int ii = 0; ii < 4; ++ii) {                                 \
      int i = wv * 4 + ii;                                                             \
      int r = i * 8 + sr_lane;                                                         \
      int gr = (lane & 7) ^ (r & 7);                                                   \
      int grow = nh * 4096 + (r >> 2) * 64 + (r & 3) * 16 + u;                         \
      GLDS(s + (size_t)(b * 32768 + grow) * 512 + (kt) + gr * 4, Sb_ + i * 1024);      \
    }                                                                                  \
    {                                                                                  \
      const u16* wsrc = (wv < 4) ? WtK : WtV;                                          \
      char* Wb_ = LDS + ((wv < 4) ? 65536 : 73728) + (buf)*4096;                       \
      int i = wv & 3;                                                                  \
      int row = i * 16 + wrow_l;                                                       \
      int ks8 = (lane & 3) ^ (row & 3);                                                \
      GLDS(wsrc + (size_t)(cg * 64 + row) * 512 + (kt) + ks8 * 8, Wb_ + i * 1024);     \
    }                                                                                  \
  }

  STAGEF(0, 0);

  for (int ki = 0; ki < 16; ++ki) {
    int cur = ki & 1;
    if (ki < 15) {
      STAGEF(cur ^ 1, (ki + 1) * 32);
      asm volatile("s_waitcnt vmcnt(5)" ::: "memory");
    } else {
      asm volatile("s_waitcnt vmcnt(0)" ::: "memory");
    }
    SBAR();
    __builtin_amdgcn_s_barrier();
    SBAR();

    const float* Sb = (const float*)(LDS + cur * 32768);
    const u16* Kb = (const u16*)(LDS + 65536 + cur * 4096);
    const u16* Vb = (const u16*)(LDS + 73728 + cur * 4096);
    bf16x8 af[2], bkf[4], bvf[4];
#pragma unroll
    for (int i = 0; i < 2; ++i) {
      int r = wv * 32 + i * 16 + fr;
      int p0 = (2 * kg) ^ (r & 7), p1 = p0 ^ 1;
      f32x4 a0 = *(const f32x4*)&Sb[r * 32 + p0 * 4];
      f32x4 a1 = *(const f32x4*)&Sb[r * 32 + p1 * 4];
      union { bf16x8 v; u32 w[4]; } uu;
      uu.w[0] = cvt_pk(a0[0], a0[1]);
      uu.w[1] = cvt_pk(a0[2], a0[3]);
      uu.w[2] = cvt_pk(a1[0], a1[1]);
      uu.w[3] = cvt_pk(a1[2], a1[3]);
      af[i] = uu.v;
    }
#pragma unroll
    for (int j = 0; j < 4; ++j) {
      int r = j * 16 + fr;
      int pos = kg ^ (r & 3);
      bkf[j] = *(const bf16x8*)&Kb[r * 32 + pos * 8];
      bvf[j] = *(const bf16x8*)&Vb[r * 32 + pos * 8];
    }
#pragma unroll
    for (int i = 0; i < 2; ++i)
#pragma unroll
      for (int j = 0; j < 4; ++j) {
        accK[i][j] = __builtin_amdgcn_mfma_f32_16x16x32_bf16(af[i], bkf[j], accK[i][j], 0, 0, 0);
        accV[i][j] = __builtin_amdgcn_mfma_f32_16x16x32_bf16(af[i], bvf[j], accV[i][j], 0, 0, 0);
      }

    SBAR();
    __builtin_amdgcn_s_barrier();
    SBAR();
  }
#undef STAGEF

  // ---- P2: panels -> LDS ----
#pragma unroll
  for (int i = 0; i < 2; ++i)
#pragma unroll
    for (int rr = 0; rr < 4; ++rr) {
      int row = wv * 32 + i * 16 + kg * 4 + rr;
#pragma unroll
      for (int j = 0; j < 4; ++j) {
        int col = j * 16 + fr;
        Klds[row * 68 + col] = f2b(accK[i][j][rr] + bkr[j]);
        Vlds[col * 264 + row] = f2b(accV[i][j][rr] + bvr[j]);
      }
    }
  __syncthreads();

  // ---- P3: QK (lane=c, wave=(p,dh)) ----
  float sc[4] = {0.f, 0.f, 0.f, 0.f};
#pragma unroll
  for (int dd = 0; dd < 32; ++dd) {
    int d = dh * 32 + dd;
    u32 word = qv[dd >> 3][(dd >> 1) & 3];
    float qd = (dd & 1) ? b2f_hi(word) : b2f_lo(word);
    int rb = d * 4;
#pragma unroll
    for (int ks = 0; ks < 4; ++ks) sc[ks] += qd * b2f(Klds[(rb + ks) * 68 + lane]);
  }
#pragma unroll
  for (int ks = 0; ks < 4; ++ks) Xf[wv * 256 + ks * 64 + lane] = sc[ks];
  __syncthreads();

  float a[4];
  {
    int pw = p3p * 2;
    float sv[4];
#pragma unroll
    for (int ks = 0; ks < 4; ++ks)
      sv[ks] = (Xf[pw * 256 + ks * 64 + lane] + Xf[(pw + 1) * 256 + ks * 64 + lane]) * 0.125f +
               br[ks];
    float mx = fmaxf(fmaxf(sv[0], sv[1]), fmaxf(sv[2], sv[3]));
    float e0 = __expf(sv[0] - mx), e1 = __expf(sv[1] - mx), e2 = __expf(sv[2] - mx),
          e3 = __expf(sv[3] - mx);
    float inv = 1.f / (e0 + e1 + e2 + e3);
    a[0] = e0 * inv; a[1] = e1 * inv; a[2] = e2 * inv; a[3] = e3 * inv;
  }
  if (dh == 0) {
#pragma unroll
    for (int ks = 0; ks < 4; ++ks) alds[(p3p * 4 + ks) * 64 + lane] = a[ks];
  }
  __syncthreads();

  // ---- PV: lane = out channel; wave handles its (p, c-half) ----
  float* ob = out + (size_t)(b * 32768 + p3p * 8192 + u * 512 + cg * 64) * 512 + nh * 64 + lane;
#pragma unroll
  for (int cc = 0; cc < 32; ++cc) {
    int c = dh * 32 + cc;
    u16x4 vvv = *(const u16x4*)&Vlds[c * 264 + lane * 4];
    float a0 = alds[(p3p * 4 + 0) * 64 + c];
    float a1 = alds[(p3p * 4 + 1) * 64 + c];
    float a2 = alds[(p3p * 4 + 2) * 64 + c];
    float a3 = alds[(p3p * 4 + 3) * 64 + c];
    float o = a0 * b2f(vvv[0]) + a1 * b2f(vvv[1]) + a2 * b2f(vvv[2]) + a3 * b2f(vvv[3]);
    ob[(size_t)c * 512] = o;
  }
}

// ---------------- launch ----------------
extern "C" void kernel_launch(void* const* d_in, const int* in_sizes, int n_in,
                              void* d_out, int out_size, void* d_ws, size_t ws_size,
                              hipStream_t stream) {
  (void)in_sizes; (void)n_in; (void)out_size; (void)ws_size;
  const float* s     = (const float*)d_in[0];
  const float* x     = (const float*)d_in[1];
  const float* s_pos = (const float*)d_in[2];
  const float* x_pos = (const float*)d_in[3];
  const float* Wq = (const float*)d_in[4];  const float* bq = (const float*)d_in[5];
  const float* Wk = (const float*)d_in[6];  const float* bk = (const float*)d_in[7];
  const float* Wv = (const float*)d_in[8];  const float* bv = (const float*)d_in[9];
  const float* pw1 = (const float*)d_in[10]; const float* pb1 = (const float*)d_in[11];
  const float* bng = (const float*)d_in[12]; const float* bnb = (const float*)d_in[13];
  const float* bnm = (const float*)d_in[14]; const float* bnv = (const float*)d_in[15];
  const float* pw2 = (const float*)d_in[16]; const float* pb2 = (const float*)d_in[17];
  float* out = (float*)d_out;

  char* ws = (char*)d_ws;
  u16* Qt = (u16*)ws;                        // 67,108,864 B
  float* biasw = (float*)(ws + 67108864);    //  8,388,608 B
  u16* Wt = (u16*)(ws + 75497472);           //  1,572,864 B

  wt_kernel<<<dim3(1024, 3), 256, 0, stream>>>(Wq, Wk, Wv, Wt);
  bias_kernel<<<dim3(256), 256, 0, stream>>>(x_pos, s_pos, pw1, pb1, bng, bnb, bnm, bnv,
                                             pw2, pb2, biasw);
  gemm_kernel<<<dim3(2048), 256, 0, stream>>>(x, Wt, bq, Qt);
  fused_attn_kernel<<<dim3(2048), 512, 0, stream>>>(s, Wt + 262144, Wt + 524288, bk, bv,
                                                    Qt, biasw, out);
}